// Round 5
// baseline (49.806 us; speedup 1.0000x reference)
//
#include <hip/hip_runtime.h>
#include <math.h>

#define BS 8
#define N_PTS 8192
#define N_SAMPLES 2048
#define TA 128                    // threads in min kernel
#define SPT 16                    // samples per thread: 128*16 = 2048 = full batch
#define PSPLIT 128
#define CHUNK (N_PTS / PSPLIT)    // 64 points per block

// ws layout: [0, PART_ELEMS) float partial mins [2][BS][PSPLIT][N_SAMPLES] (16 MiB)
//            then [64] float tile sums
#define PART_ELEMS (2 * BS * PSPLIT * N_SAMPLES)

#define PIN4(v) asm volatile("" : "+v"(v.x), "+v"(v.y), "+v"(v.z), "+v"(v.w))

// Kernel A: per (batch, point-chunk) block. Metric per pair:
//   f = |p|^2 - 2 s.p   (monotone in d^2 for fixed s; d^2 = f + |s|^2)
// Points staged in LDS with |p|^2 precomputed; point values and sample regs
// are PINNED via empty asm so the compiler cannot interchange loops or
// rematerialize LDS reads (R0/R4 VGPR counts proved it was doing exactly
// that). No atomics: each block writes its own partial-min slice.
__global__ __launch_bounds__(TA, 1)
void chamfer_min_kernel(const float* __restrict__ gts,
                        const float* __restrict__ preds,
                        const float* __restrict__ grid,
                        float* __restrict__ part)
{
    const int bid = blockIdx.x;
    const int b   = bid >> 7;           // / PSPLIT
    const int pc  = bid & (PSPLIT - 1);
    const int t   = threadIdx.x;

    __shared__ float4 ldsP[CHUNK];
    __shared__ float4 ldsG[CHUNK];

    // Staging: threads 0..63 stage preds chunk, 64..127 stage gts chunk.
    {
        const int j = t & (CHUNK - 1);
        const float* src = ((t < CHUNK) ? preds : gts)
                         + ((size_t)b * N_PTS + (size_t)pc * CHUNK + j) * 3;
        const float x = src[0], y = src[1], z = src[2];
        const float4 v = make_float4(x, y, z, fmaf(x, x, fmaf(y, y, z * z)));
        if (t < CHUNK) ldsP[j] = v; else ldsG[j] = v;
    }

    // Per-thread samples (coalesced: s = k*128 + t); ns = -2*s, s2 = |s|^2.
    float nsx[SPT], nsy[SPT], nsz[SPT], s2[SPT], mP[SPT], mG[SPT];
    {
        const float* grow = grid + (size_t)b * N_SAMPLES * 3;
#pragma unroll
        for (int k = 0; k < SPT; ++k) {
            const int s = k * TA + t;
            const float x = grow[s * 3 + 0];
            const float y = grow[s * 3 + 1];
            const float z = grow[s * 3 + 2];
            s2[k]  = fmaf(x, x, fmaf(y, y, z * z));
            nsx[k] = -2.0f * x;
            nsy[k] = -2.0f * y;
            nsz[k] = -2.0f * z;
            asm volatile("" : "+v"(nsx[k]), "+v"(nsy[k]), "+v"(nsz[k]), "+v"(s2[k]));
            mP[k] = 3.0e38f;
            mG[k] = 3.0e38f;
        }
    }

    __syncthreads();

    // Main loop: 2 points per side per iter; 3 fma/pair + min3 shared over 2.
#pragma unroll 1
    for (int j = 0; j < CHUNK; j += 2) {
        float4 p0 = ldsP[j], p1 = ldsP[j + 1];
        float4 g0 = ldsG[j], g1 = ldsG[j + 1];
        PIN4(p0); PIN4(p1); PIN4(g0); PIN4(g1);
#pragma unroll
        for (int k = 0; k < SPT; ++k) {
            const float x = nsx[k], y = nsy[k], z = nsz[k];
            const float t0 = fmaf(p0.x, x, fmaf(p0.y, y, fmaf(p0.z, z, p0.w)));
            const float t1 = fmaf(p1.x, x, fmaf(p1.y, y, fmaf(p1.z, z, p1.w)));
            mP[k] = fminf(fminf(t0, t1), mP[k]);   // -> v_min3_f32
            const float u0 = fmaf(g0.x, x, fmaf(g0.y, y, fmaf(g0.z, z, g0.w)));
            const float u1 = fmaf(g1.x, x, fmaf(g1.y, y, fmaf(g1.z, z, g1.w)));
            mG[k] = fminf(fminf(u0, u1), mG[k]);
        }
    }

    // Write partial mins as true clamped d^2 (coalesced dword stores).
    float* pp = part + (((size_t)b)           * PSPLIT + pc) * N_SAMPLES;
    float* pg = part + (((size_t)(BS + b))    * PSPLIT + pc) * N_SAMPLES;
#pragma unroll
    for (int k = 0; k < SPT; ++k) {
        const int s = k * TA + t;
        pp[s] = fmaxf(mP[k] + s2[k], 0.0f);
        pg[s] = fmaxf(mG[k] + s2[k], 0.0f);
    }
}

// Kernel B: per (batch, sample-tile of 256) block, min over the 128 partials
// for each side, then |sqrt - sqrt|, fixed-tree block sum -> tile sum.
__global__ __launch_bounds__(256, 1)
void chamfer_reduce_kernel(const float* __restrict__ part,
                           float* __restrict__ tsum)
{
    const int blk  = blockIdx.x;       // 0..63
    const int b    = blk >> 3;
    const int tile = blk & 7;
    const int t    = threadIdx.x;
    const int s    = tile * 256 + t;

    const float* pp = part + ((size_t)b)        * PSPLIT * N_SAMPLES + s;
    const float* pg = part + ((size_t)(BS + b)) * PSPLIT * N_SAMPLES + s;

    float mp = 3.0e38f, mg = 3.0e38f;
#pragma unroll 4
    for (int pc = 0; pc < PSPLIT; ++pc) {
        mp = fminf(mp, pp[(size_t)pc * N_SAMPLES]);
        mg = fminf(mg, pg[(size_t)pc * N_SAMPLES]);
    }

    float v = fabsf(sqrtf(mp) - sqrtf(mg));

    // fixed-tree reduction: wave shuffle, then cross-wave via LDS
#pragma unroll
    for (int off = 32; off > 0; off >>= 1)
        v += __shfl_down(v, off, 64);

    __shared__ float w[4];
    if ((t & 63) == 0) w[t >> 6] = v;
    __syncthreads();
    if (t == 0) tsum[blk] = (w[0] + w[1]) + (w[2] + w[3]);
}

// Kernel C: combine 8 tile sums per batch (fixed order) -> mean.
__global__ __launch_bounds__(64)
void chamfer_out_kernel(const float* __restrict__ tsum,
                        float* __restrict__ out)
{
    const int b = threadIdx.x;
    if (b < BS) {
        float tot = 0.0f;
#pragma unroll
        for (int i = 0; i < 8; ++i) tot += tsum[b * 8 + i];
        out[b] = tot * (1.0f / (float)N_SAMPLES);
    }
}

extern "C" void kernel_launch(void* const* d_in, const int* in_sizes, int n_in,
                              void* d_out, int out_size, void* d_ws, size_t ws_size,
                              hipStream_t stream)
{
    const float* gts   = (const float*)d_in[0];
    const float* preds = (const float*)d_in[1];
    const float* grid  = (const float*)d_in[2];
    float* out  = (float*)d_out;
    float* part = (float*)d_ws;
    float* tsum = part + PART_ELEMS;

    chamfer_min_kernel<<<dim3(BS * PSPLIT), dim3(TA), 0, stream>>>(gts, preds, grid, part);
    chamfer_reduce_kernel<<<dim3(64), dim3(256), 0, stream>>>(part, tsum);
    chamfer_out_kernel<<<dim3(1), dim3(64), 0, stream>>>(tsum, out);
}

// Round 6
// 36.175 us; speedup vs baseline: 1.3768x; 1.3768x over previous
//
#include <hip/hip_runtime.h>
#include <math.h>

#define BS 8
#define N_PTS 8192
#define N_SAMPLES 2048
#define TA 512                    // threads in min kernel (8 waves/block)
#define SPT 4                     // samples per thread: 512*4 = 2048 = full batch
#define PSPLIT 64
#define CHUNK (N_PTS / PSPLIT)    // 128 points per block

// ws layout: part[2][BS][PSPLIT][N_SAMPLES] floats (8 MiB), then tsum[64]
#define PART_ELEMS (2 * BS * PSPLIT * N_SAMPLES)

// Kernel A: per (batch, point-chunk) block. Metric per pair:
//   f = |p|^2 - 2 s.p   (monotone in d^2 for fixed s; d^2 = f + |s|^2)
// Points staged in LDS ({x,y,z,|p|^2}); all main-loop LDS reads are
// wave-uniform broadcasts (conflict-free). SPT=4 keeps live state ~60 VGPR
// (no spill — R4's VGPR=56 vs 96-float state proved SPT=16 spilled), and
// 512-thr blocks give 4 waves/SIMD to hide fma dep chains. NO atomics:
// R4's WRITE_SIZE=16MB showed every atomicMin writes through to the
// coherence point; disjoint partial-min slices stream at full BW instead.
__global__ __launch_bounds__(TA, 4)
void chamfer_min_kernel(const float* __restrict__ gts,
                        const float* __restrict__ preds,
                        const float* __restrict__ grid,
                        float* __restrict__ part)
{
    const int bid = blockIdx.x;
    const int b   = bid >> 6;           // / PSPLIT
    const int pc  = bid & (PSPLIT - 1);
    const int t   = threadIdx.x;

    __shared__ float4 ldsP[CHUNK];
    __shared__ float4 ldsG[CHUNK];

    // Staging: threads 0..127 stage preds chunk, 128..255 stage gts chunk.
    if (t < 2 * CHUNK) {
        const int j = t & (CHUNK - 1);
        const float* src = ((t < CHUNK) ? preds : gts)
                         + ((size_t)b * N_PTS + (size_t)pc * CHUNK + j) * 3;
        const float x = src[0], y = src[1], z = src[2];
        const float4 v = make_float4(x, y, z, fmaf(x, x, fmaf(y, y, z * z)));
        if (t < CHUNK) ldsP[j] = v; else ldsG[j] = v;
    }

    // Per-thread samples (coalesced: s = k*512 + t); ns = -2*s.
    float nsx[SPT], nsy[SPT], nsz[SPT], mP[SPT], mG[SPT];
    {
        const float* grow = grid + (size_t)b * N_SAMPLES * 3;
#pragma unroll
        for (int k = 0; k < SPT; ++k) {
            const int s = k * TA + t;
            nsx[k] = -2.0f * grow[s * 3 + 0];
            nsy[k] = -2.0f * grow[s * 3 + 1];
            nsz[k] = -2.0f * grow[s * 3 + 2];
            mP[k] = 3.0e38f;
            mG[k] = 3.0e38f;
        }
    }

    __syncthreads();

    // Main loop: 2 points per side per iter; 3 fma/pair + min3 shared over 2.
#pragma unroll 4
    for (int j = 0; j < CHUNK; j += 2) {
        const float4 p0 = ldsP[j], p1 = ldsP[j + 1];
        const float4 g0 = ldsG[j], g1 = ldsG[j + 1];
#pragma unroll
        for (int k = 0; k < SPT; ++k) {
            const float x = nsx[k], y = nsy[k], z = nsz[k];
            const float t0 = fmaf(p0.x, x, fmaf(p0.y, y, fmaf(p0.z, z, p0.w)));
            const float t1 = fmaf(p1.x, x, fmaf(p1.y, y, fmaf(p1.z, z, p1.w)));
            mP[k] = fminf(fminf(t0, t1), mP[k]);   // -> v_min3_f32
            const float u0 = fmaf(g0.x, x, fmaf(g0.y, y, fmaf(g0.z, z, g0.w)));
            const float u1 = fmaf(g1.x, x, fmaf(g1.y, y, fmaf(g1.z, z, g1.w)));
            mG[k] = fminf(fminf(u0, u1), mG[k]);
        }
    }

    // Disjoint slices, coalesced dword streaming stores of clamped d^2.
    float* pp = part + (((size_t)b)        * PSPLIT + pc) * N_SAMPLES;
    float* pg = part + (((size_t)(BS + b)) * PSPLIT + pc) * N_SAMPLES;
#pragma unroll
    for (int k = 0; k < SPT; ++k) {
        const int s = k * TA + t;
        const float s2 = 0.25f * fmaf(nsx[k], nsx[k], fmaf(nsy[k], nsy[k], nsz[k] * nsz[k]));
        pp[s] = fmaxf(mP[k] + s2, 0.0f);
        pg[s] = fmaxf(mG[k] + s2, 0.0f);
    }
}

// Kernel B: per (batch, sample-tile of 256) block: min over 64 partials per
// side, |sqrt - sqrt|, fixed-tree block sum -> tsum[blk]. Deterministic.
__global__ __launch_bounds__(256, 1)
void chamfer_reduce_kernel(const float* __restrict__ part,
                           float* __restrict__ tsum)
{
    const int blk  = blockIdx.x;       // 0..63
    const int b    = blk >> 3;
    const int tile = blk & 7;
    const int t    = threadIdx.x;
    const int s    = tile * 256 + t;

    const float* pp = part + ((size_t)b)        * PSPLIT * N_SAMPLES + s;
    const float* pg = part + ((size_t)(BS + b)) * PSPLIT * N_SAMPLES + s;

    float mp = 3.0e38f, mg = 3.0e38f;
#pragma unroll 8
    for (int pc = 0; pc < PSPLIT; ++pc) {
        mp = fminf(mp, pp[(size_t)pc * N_SAMPLES]);
        mg = fminf(mg, pg[(size_t)pc * N_SAMPLES]);
    }

    float v = fabsf(sqrtf(mp) - sqrtf(mg));

#pragma unroll
    for (int off = 32; off > 0; off >>= 1)
        v += __shfl_down(v, off, 64);

    __shared__ float w[4];
    if ((t & 63) == 0) w[t >> 6] = v;
    __syncthreads();
    if (t == 0) tsum[blk] = (w[0] + w[1]) + (w[2] + w[3]);
}

// Kernel C: combine 8 tile sums per batch (fixed order) -> mean.
__global__ __launch_bounds__(64)
void chamfer_out_kernel(const float* __restrict__ tsum,
                        float* __restrict__ out)
{
    const int b = threadIdx.x;
    if (b < BS) {
        float tot = 0.0f;
#pragma unroll
        for (int i = 0; i < 8; ++i) tot += tsum[b * 8 + i];
        out[b] = tot * (1.0f / (float)N_SAMPLES);
    }
}

extern "C" void kernel_launch(void* const* d_in, const int* in_sizes, int n_in,
                              void* d_out, int out_size, void* d_ws, size_t ws_size,
                              hipStream_t stream)
{
    const float* gts   = (const float*)d_in[0];
    const float* preds = (const float*)d_in[1];
    const float* grid  = (const float*)d_in[2];
    float* out  = (float*)d_out;
    float* part = (float*)d_ws;
    float* tsum = part + PART_ELEMS;

    chamfer_min_kernel<<<dim3(BS * PSPLIT), dim3(TA), 0, stream>>>(gts, preds, grid, part);
    chamfer_reduce_kernel<<<dim3(64), dim3(256), 0, stream>>>(part, tsum);
    chamfer_out_kernel<<<dim3(1), dim3(64), 0, stream>>>(tsum, out);
}